// Round 6
// baseline (2445.979 us; speedup 1.0000x reference)
//
#include <hip/hip_runtime.h>

// SurvModel: x=relu(BN(in@W1+b1)); h=tanh(BN(x@Watt1+batt1)); s=h@Watt2+batt2;
// A=softmax_N(s); top64 by A desc (stable); zs=x[top]*softmax(A[top]);
// zq/zk/zv=zs@W*; zw=softmax(zq@zk^T)@zv; out=relu(zw.flat@Wz+bz)@Wf+bf.
// Split-fp32 (bf16 hi/lo, 3 MFMAs) keeps scores ~1e-6 accurate (top-64 gap ~1.3e-3).
// R6: BARRIER-FREE K-loop. Each wave independent: 32x64 output, A global->VGPR
// (frag layout == natural per-lane load, imm offsets), B global->VGPR from plain
// W1T in L2. No LDS/no s_barrier/no waitcnt in loop -> TLP (12 waves/CU) hides
// latency instead of lockstep pipelining. LDS only for phase-2 (48KB, 3 blk/CU).

#define NN   131072
#define DIN  768
#define DH   128
#define DA   32

using f32x4  = __attribute__((ext_vector_type(4))) float;
using bf16x8 = __attribute__((ext_vector_type(8))) __bf16;

// workspace byte offsets
#define WS_S      0            // float[131072] scores
#define WS_PZ8    524288       // float[8192] per-wave sum(exp(s))
#define WS_HIST   557056       // int[4096]
#define WS_MISC   573440       // [0]=Z f32, [2]=cnt int, [3]=bstar int
#define WS_CIDX   573504       // int[512]
#define WS_CS     575552       // float[512]
#define WS_ORDER  577600       // int[64]
#define WS_W      577856       // float[64]
#define WS_ZQ     578112       // float[2048]
#define WS_ZK     586304       // float[2048]
#define WS_ZV     594496       // float[2048]
#define WS_ZW     602688       // float[2048]
#define WS_W1T    610944       // 24*16384 B bf16 hi/lo W1, plain [kc][col][u] layout

__device__ __forceinline__ int s_bin(float s) {
  int b = (int)((s + 6.0f) * (4096.0f / 12.0f));
  return b < 0 ? 0 : (b > 4095 ? 4095 : b);
}

// K0: W1 -> bf16 hi/lo, [kc][col][u]: u 0..3 = hi of k in [8u,8u+8), u 4..7 = lo.
// Also zero hist+misc.
__global__ void k_prep(const float* __restrict__ W1, char* __restrict__ ws) {
  int T = blockIdx.x * 256 + threadIdx.x;       // 0..24575
  if (T < 4112) ((int*)(ws + WS_HIST))[T] = 0;
  int u = T & 7, col = (T >> 3) & 127, kc = T >> 10;
  bf16x8 ov;
  #pragma unroll
  for (int j = 0; j < 8; ++j) {
    int k = (u & 3) * 8 + j;
    float v = W1[(size_t)(kc * 32 + k) * 128 + col];
    __bf16 h = (__bf16)v;
    ov[j] = (u < 4) ? h : (__bf16)(v - (float)h);
  }
  *(bf16x8*)(ws + WS_W1T + (size_t)kc * 16384 + col * 128 + u * 16) = ov;
}

// ---------------- K1: main GEMM + h + scores ----------------
__global__ __launch_bounds__(256, 3) void k_main(
    const float* __restrict__ inp,
    const float* __restrict__ b1, const float* __restrict__ g1, const float* __restrict__ be1,
    const float* __restrict__ Watt1, const float* __restrict__ batt1,
    const float* __restrict__ g2, const float* __restrict__ be2,
    const float* __restrict__ Watt2, const float* __restrict__ batt2,
    char* __restrict__ ws)
{
  // LDS 48K: [0,32K) x-tile (phase 2 only) | [32K,48K) Watt1
  __shared__ __align__(16) char lds[49152];
  float* s_out = (float*)(ws + WS_S);
  float* pz8   = (float*)(ws + WS_PZ8);
  int*   hist  = (int*)(ws + WS_HIST);
  const char* w1t = ws + WS_W1T;

  const int t = threadIdx.x;
  const int l = t & 63;
  const int wid = t >> 6;
  const int wr = wid >> 1, wc = wid & 1;       // wave: rows wr*32+[0,32), cols wc*64+[0,64)
  const int r15 = l & 15, kg = l >> 4;
  const int blockRow = blockIdx.x * 64;
  const float inv = 1.0f / sqrtf(1.0f + 1e-5f);

  float* wat = (float*)(lds + 32768);
  for (int i = t; i < DH * DA; i += 256) wat[i] = Watt1[i];   // consumed after syncthreads

  // A bases: strip 0 rows blockRow+wr*32+r15, strip 1 = +16 rows. kg*8 floats in.
  const char* aB0 = (const char*)(inp + (size_t)(blockRow + wr * 32 + r15) * DIN) + kg * 32;
  const char* aB1 = aB0 + 16 * 3072;
  // B base: col block wc*64; lane col offset r15; unit kg (hi), +64 (lo)
  const char* bP0 = w1t + (wc * 64 + r15) * 128 + kg * 16;

  f32x4 acc[2][4];
  #pragma unroll
  for (int mi = 0; mi < 2; ++mi)
    #pragma unroll
    for (int ni = 0; ni < 4; ++ni)
      #pragma unroll
      for (int q = 0; q < 4; ++q) acc[mi][ni][q] = 0.0f;

#define CVT(ahi, alo, c0, c1) do { \
    _Pragma("unroll") \
    for (int j = 0; j < 4; ++j) { \
      float x0 = (c0)[j]; __bf16 h0 = (__bf16)x0; \
      (ahi)[j] = h0; (alo)[j] = (__bf16)(x0 - (float)h0); \
      float x1 = (c1)[j]; __bf16 h1 = (__bf16)x1; \
      (ahi)[4 + j] = h1; (alo)[4 + j] = (__bf16)(x1 - (float)h1); \
    } \
  } while (0)

#define BODY(kc_, c0, c1, c2, c3, n0, n1, n2, n3) do { \
    const char* bb  = bP0 + (size_t)(kc_) * 16384; \
    bf16x8 bh0 = *(const bf16x8*)(bb);          bf16x8 bl0 = *(const bf16x8*)(bb + 64); \
    bf16x8 bh1 = *(const bf16x8*)(bb + 2048);   bf16x8 bl1 = *(const bf16x8*)(bb + 2112); \
    bf16x8 bh2 = *(const bf16x8*)(bb + 4096);   bf16x8 bl2 = *(const bf16x8*)(bb + 4160); \
    bf16x8 bh3 = *(const bf16x8*)(bb + 6144);   bf16x8 bl3 = *(const bf16x8*)(bb + 6208); \
    if ((kc_) < 23) { \
      n0 = *(const f32x4*)(aB0 + ((kc_) + 1) * 128); \
      n1 = *(const f32x4*)(aB0 + ((kc_) + 1) * 128 + 16); \
      n2 = *(const f32x4*)(aB1 + ((kc_) + 1) * 128); \
      n3 = *(const f32x4*)(aB1 + ((kc_) + 1) * 128 + 16); \
    } \
    bf16x8 ah0, al0, ah1, al1; \
    CVT(ah0, al0, c0, c1); \
    CVT(ah1, al1, c2, c3); \
    acc[0][0] = __builtin_amdgcn_mfma_f32_16x16x32_bf16(ah0, bh0, acc[0][0], 0, 0, 0); \
    acc[0][0] = __builtin_amdgcn_mfma_f32_16x16x32_bf16(ah0, bl0, acc[0][0], 0, 0, 0); \
    acc[0][0] = __builtin_amdgcn_mfma_f32_16x16x32_bf16(al0, bh0, acc[0][0], 0, 0, 0); \
    acc[0][1] = __builtin_amdgcn_mfma_f32_16x16x32_bf16(ah0, bh1, acc[0][1], 0, 0, 0); \
    acc[0][1] = __builtin_amdgcn_mfma_f32_16x16x32_bf16(ah0, bl1, acc[0][1], 0, 0, 0); \
    acc[0][1] = __builtin_amdgcn_mfma_f32_16x16x32_bf16(al0, bh1, acc[0][1], 0, 0, 0); \
    acc[0][2] = __builtin_amdgcn_mfma_f32_16x16x32_bf16(ah0, bh2, acc[0][2], 0, 0, 0); \
    acc[0][2] = __builtin_amdgcn_mfma_f32_16x16x32_bf16(ah0, bl2, acc[0][2], 0, 0, 0); \
    acc[0][2] = __builtin_amdgcn_mfma_f32_16x16x32_bf16(al0, bh2, acc[0][2], 0, 0, 0); \
    acc[0][3] = __builtin_amdgcn_mfma_f32_16x16x32_bf16(ah0, bh3, acc[0][3], 0, 0, 0); \
    acc[0][3] = __builtin_amdgcn_mfma_f32_16x16x32_bf16(ah0, bl3, acc[0][3], 0, 0, 0); \
    acc[0][3] = __builtin_amdgcn_mfma_f32_16x16x32_bf16(al0, bh3, acc[0][3], 0, 0, 0); \
    acc[1][0] = __builtin_amdgcn_mfma_f32_16x16x32_bf16(ah1, bh0, acc[1][0], 0, 0, 0); \
    acc[1][0] = __builtin_amdgcn_mfma_f32_16x16x32_bf16(ah1, bl0, acc[1][0], 0, 0, 0); \
    acc[1][0] = __builtin_amdgcn_mfma_f32_16x16x32_bf16(al1, bh0, acc[1][0], 0, 0, 0); \
    acc[1][1] = __builtin_amdgcn_mfma_f32_16x16x32_bf16(ah1, bh1, acc[1][1], 0, 0, 0); \
    acc[1][1] = __builtin_amdgcn_mfma_f32_16x16x32_bf16(ah1, bl1, acc[1][1], 0, 0, 0); \
    acc[1][1] = __builtin_amdgcn_mfma_f32_16x16x32_bf16(al1, bh1, acc[1][1], 0, 0, 0); \
    acc[1][2] = __builtin_amdgcn_mfma_f32_16x16x32_bf16(ah1, bh2, acc[1][2], 0, 0, 0); \
    acc[1][2] = __builtin_amdgcn_mfma_f32_16x16x32_bf16(ah1, bl2, acc[1][2], 0, 0, 0); \
    acc[1][2] = __builtin_amdgcn_mfma_f32_16x16x32_bf16(al1, bh2, acc[1][2], 0, 0, 0); \
    acc[1][3] = __builtin_amdgcn_mfma_f32_16x16x32_bf16(ah1, bh3, acc[1][3], 0, 0, 0); \
    acc[1][3] = __builtin_amdgcn_mfma_f32_16x16x32_bf16(ah1, bl3, acc[1][3], 0, 0, 0); \
    acc[1][3] = __builtin_amdgcn_mfma_f32_16x16x32_bf16(al1, bh3, acc[1][3], 0, 0, 0); \
  } while (0)

  // A ping-pong register sets (all names static — rule #20)
  f32x4 aA0, aA1, aA2, aA3, aB0r, aB1r, aB2r, aB3r;
  aA0 = *(const f32x4*)(aB0);      aA1 = *(const f32x4*)(aB0 + 16);
  aA2 = *(const f32x4*)(aB1);      aA3 = *(const f32x4*)(aB1 + 16);

  #pragma unroll
  for (int kc = 0; kc < 24; kc += 2) {
    BODY(kc,     aA0, aA1, aA2, aA3, aB0r, aB1r, aB2r, aB3r);
    BODY(kc + 1, aB0r, aB1r, aB2r, aB3r, aA0, aA1, aA2, aA3);
  }
#undef BODY
#undef CVT

  // epilogue: BN + relu -> x tile (64 rows x 128 cols fp32) into LDS (swizzled)
  #pragma unroll
  for (int mi = 0; mi < 2; ++mi)
    #pragma unroll
    for (int ni = 0; ni < 4; ++ni) {
      int col = wc * 64 + ni * 16 + r15;
      float b1c = b1[col], s1c = g1[col] * inv, be1c = be1[col];
      #pragma unroll
      for (int q = 0; q < 4; ++q) {
        int row = wr * 32 + mi * 16 + kg * 4 + q;
        float xv = fmaxf((acc[mi][ni][q] + b1c) * s1c + be1c, 0.0f);
        *(float*)(lds + row * 512 + ((col * 4) ^ ((row & 31) << 4))) = xv;
      }
    }
  __syncthreads();

  // h = tanh(BN(x@Watt1)); s = h@Watt2 + batt2; Z partials; histogram
  {
    const int row = t >> 2, q4 = t & 3;     // 64 rows, 4 threads/row, 8 a-dims each
    const int rsw = (row & 31) << 4;
    float hacc[8];
    #pragma unroll
    for (int a = 0; a < 8; ++a) hacc[a] = 0.0f;
    const char* xrow = lds + row * 512;
    const float* watt = wat + q4 * 8;
    for (int cb = 0; cb < 128; cb += 4) {
      f32x4 xv = *(const f32x4*)(xrow + ((cb * 4) ^ rsw));
      #pragma unroll
      for (int u = 0; u < 4; ++u) {
        const float* wrow = watt + (cb + u) * 32;
        f32x4 w0 = *(const f32x4*)(wrow);
        f32x4 w1 = *(const f32x4*)(wrow + 4);
        float xs = xv[u];
        #pragma unroll
        for (int q = 0; q < 4; ++q) {
          hacc[q]     += xs * w0[q];
          hacc[4 + q] += xs * w1[q];
        }
      }
    }
    float partial = 0.0f;
    #pragma unroll
    for (int a = 0; a < 8; ++a) {
      int ai = q4 * 8 + a;
      float hv = tanhf((hacc[a] + batt1[ai]) * (g2[ai] * inv) + be2[ai]);
      partial += hv * Watt2[ai];
    }
    partial += __shfl_xor(partial, 1, 64);
    partial += __shfl_xor(partial, 2, 64);
    float ev = 0.0f;
    if (q4 == 0) {
      float sv = partial + batt2[0];
      s_out[blockRow + row] = sv;
      atomicAdd(&hist[s_bin(sv)], 1);
      ev = expf(sv);
    }
    #pragma unroll
    for (int off = 32; off >= 1; off >>= 1) ev += __shfl_xor(ev, off, 64);
    if (l == 0) pz8[blockIdx.x * 4 + wid] = ev;
  }
}

// ---------------- K2: Z reduce + histogram threshold ----------------
__global__ void k_reduce(char* __restrict__ ws) {
  float* pz8 = (float*)(ws + WS_PZ8);
  int* hist = (int*)(ws + WS_HIST);
  float* miscf = (float*)(ws + WS_MISC);
  int* misci = (int*)(ws + WS_MISC);
  const int t = threadIdx.x;
  __shared__ float red[256];
  __shared__ int csum[256];
  float z = 0.0f;
  for (int i = t; i < 8192; i += 256) z += pz8[i];
  red[t] = z;
  int c = 0;
  #pragma unroll
  for (int u = 0; u < 16; ++u) c += hist[t * 16 + u];
  csum[t] = c;
  __syncthreads();
  for (int off = 128; off >= 1; off >>= 1) {
    if (t < off) red[t] += red[t + off];
    __syncthreads();
  }
  if (t == 0) {
    miscf[0] = red[0];
    int cum = 0, bstar = 0;
    for (int ch = 255; ch >= 0; --ch) {
      if (cum + csum[ch] >= 64) {
        for (int b = ch * 16 + 15; b >= ch * 16; --b) {
          cum += hist[b];
          if (cum >= 64) { bstar = b; break; }
        }
        break;
      }
      cum += csum[ch];
    }
    misci[3] = bstar;
    misci[2] = 0;
  }
}

// ---------------- K3: gather candidates ----------------
__global__ void k_gather(char* __restrict__ ws) {
  const int i = blockIdx.x * 256 + threadIdx.x;
  float* s_out = (float*)(ws + WS_S);
  int* misci = (int*)(ws + WS_MISC);
  int* cidx = (int*)(ws + WS_CIDX);
  float* cs = (float*)(ws + WS_CS);
  float s = s_out[i];
  if (s_bin(s) >= misci[3]) {
    int pos = atomicAdd(&misci[2], 1);
    if (pos < 512) { cidx[pos] = i; cs[pos] = s; }
  }
}

// ---------------- K4: sort candidates, top-64 order + weights ----------------
__global__ void k_select(char* __restrict__ ws) {
  const int t = threadIdx.x;
  float* s_out = (float*)(ws + WS_S);
  int* misci = (int*)(ws + WS_MISC);
  float* miscf = (float*)(ws + WS_MISC);
  int* cidx = (int*)(ws + WS_CIDX);
  float* cs = (float*)(ws + WS_CS);
  int* order = (int*)(ws + WS_ORDER);
  float* wsel = (float*)(ws + WS_W);
  __shared__ unsigned long long keys[512];
  __shared__ float aLds[64];
  int cnt = misci[2]; if (cnt > 512) cnt = 512;
  for (int i = t; i < 512; i += 256) {
    unsigned long long kkey = 0xFFFFFFFFFFFFFFFFull;
    if (i < cnt) {
      unsigned u = __float_as_uint(cs[i]);
      u = (u & 0x80000000u) ? ~u : (u | 0x80000000u);  // ascending map
      unsigned du = ~u;                                 // descending by s
      kkey = ((unsigned long long)du << 32) | (unsigned)cidx[i];  // tie: idx asc
    }
    keys[i] = kkey;
  }
  __syncthreads();
  for (int k = 2; k <= 512; k <<= 1) {
    for (int j = k >> 1; j > 0; j >>= 1) {
      for (int i = t; i < 512; i += 256) {
        int ixj = i ^ j;
        if (ixj > i) {
          bool up = ((i & k) == 0);
          unsigned long long a = keys[i], b2 = keys[ixj];
          if (up ? (a > b2) : (a < b2)) { keys[i] = b2; keys[ixj] = a; }
        }
      }
      __syncthreads();
    }
  }
  float Z = miscf[0];
  if (t < 64) {
    int idx = (int)(keys[t] & 0xFFFFFFFFull);
    order[t] = idx;
    aLds[t] = expf(s_out[idx]) / Z;
  }
  __syncthreads();
  if (t < 64) {
    float m = aLds[0];                // sorted desc -> max
    float e = expf(aLds[t] - m);
    float sum = e;
    #pragma unroll
    for (int off = 32; off >= 1; off >>= 1) sum += __shfl_xor(sum, off, 64);
    wsel[t] = e / sum;
  }
}

// ---------------- K5: recompute x for top-64, zs, zq/zk/zv ----------------
__global__ void k_zs(const float* __restrict__ inp, const float* __restrict__ W1,
                     const float* __restrict__ b1, const float* __restrict__ g1, const float* __restrict__ be1,
                     const float* __restrict__ Wq, const float* __restrict__ Wk, const float* __restrict__ Wv,
                     char* __restrict__ ws)
{
  const int t = threadIdx.x, b = blockIdx.x;
  int* order = (int*)(ws + WS_ORDER);
  float* wsel = (float*)(ws + WS_W);
  float* zq = (float*)(ws + WS_ZQ);
  float* zk = (float*)(ws + WS_ZK);
  float* zv = (float*)(ws + WS_ZV);
  __shared__ float rowS[768];
  __shared__ float zsS[128];
  const float inv = 1.0f / sqrtf(1.0f + 1e-5f);
  int r = order[b];
  float wgt = wsel[b];
  for (int i = t; i < 768; i += 256) rowS[i] = inp[(size_t)r * 768 + i];
  __syncthreads();
  if (t < 128) {
    float d = 0.0f;
    for (int k = 0; k < 768; ++k) d += rowS[k] * W1[(size_t)k * 128 + t];
    float x = fmaxf((d + b1[t]) * (g1[t] * inv) + be1[t], 0.0f);
    zsS[t] = x * wgt;
  }
  __syncthreads();
  if (t < 96) {
    int which = t >> 5, a = t & 31;
    const float* W = (which == 0) ? Wq : ((which == 1) ? Wk : Wv);
    float d = 0.0f;
    for (int c = 0; c < 128; ++c) d += zsS[c] * W[c * 32 + a];
    float* dst = (which == 0) ? zq : ((which == 1) ? zk : zv);
    dst[b * 32 + a] = d;
  }
}

// ---------------- K6a: 64x64 attention (also zeroes d_out for K6b atomics) ----
__global__ void k_attn(char* __restrict__ ws, float* __restrict__ out) {
  const int t = threadIdx.x;
  if (t == 0) out[0] = 0.0f;
  float* zq = (float*)(ws + WS_ZQ);
  float* zk = (float*)(ws + WS_ZK);
  float* zv = (float*)(ws + WS_ZV);
  float* zw = (float*)(ws + WS_ZW);
  __shared__ float q[2048], kk[2048], v[2048], P[4096];
  for (int i = t; i < 2048; i += 256) { q[i] = zq[i]; kk[i] = zk[i]; v[i] = zv[i]; }
  __syncthreads();
  for (int o = t; o < 4096; o += 256) {
    int i = o >> 6, j = o & 63;
    float d = 0.0f;
    for (int a = 0; a < 32; ++a) d += q[i * 32 + a] * kk[j * 32 + a];
    P[o] = d;
  }
  __syncthreads();
  if (t < 64) {
    float m = -1e30f;
    for (int j = 0; j < 64; ++j) m = fmaxf(m, P[t * 64 + j]);
    float sum = 0.0f;
    for (int j = 0; j < 64; ++j) { float e = expf(P[t * 64 + j] - m); P[t * 64 + j] = e; sum += e; }
    float rs = 1.0f / sum;
    for (int j = 0; j < 64; ++j) P[t * 64 + j] *= rs;
  }
  __syncthreads();
  for (int o = t; o < 2048; o += 256) {
    int i = o >> 5, a = o & 31;
    float d = 0.0f;
    for (int j = 0; j < 64; ++j) d += P[i * 64 + j] * v[j * 32 + a];
    zw[o] = d;
  }
}

// ---------------- K6b: zw.flat @ Wz + bz, relu, dot Wf, atomic out -----------
__global__ void k_wz(const float* __restrict__ Wz, const float* __restrict__ bz,
                     const float* __restrict__ Wf, const float* __restrict__ bf_,
                     char* __restrict__ ws, float* __restrict__ out) {
  const int t = threadIdx.x, j = blockIdx.x;
  float* zw = (float*)(ws + WS_ZW);
  __shared__ float red[256];
  float p = 0.0f;
  for (int i2 = t; i2 < 2048; i2 += 256) p += zw[i2] * Wz[(size_t)i2 * 128 + j];
  red[t] = p; __syncthreads();
  for (int off = 128; off >= 1; off >>= 1) {
    if (t < off) red[t] += red[t + off];
    __syncthreads();
  }
  if (t == 0) {
    float o = fmaxf(red[0] + bz[j], 0.0f);
    float contrib = o * Wf[j] + (j == 0 ? bf_[0] : 0.0f);
    atomicAdd(out, contrib);
  }
}

extern "C" void kernel_launch(void* const* d_in, const int* in_sizes, int n_in,
                              void* d_out, int out_size, void* d_ws, size_t ws_size,
                              hipStream_t stream) {
  const float* inp   = (const float*)d_in[0];
  const float* W1    = (const float*)d_in[1];
  const float* b1    = (const float*)d_in[2];
  const float* g1    = (const float*)d_in[3];
  const float* be1   = (const float*)d_in[4];
  const float* Watt1 = (const float*)d_in[5];
  const float* batt1 = (const float*)d_in[6];
  const float* g2    = (const float*)d_in[7];
  const float* be2   = (const float*)d_in[8];
  const float* Watt2 = (const float*)d_in[9];
  const float* batt2 = (const float*)d_in[10];
  const float* Wq    = (const float*)d_in[11];
  const float* Wk    = (const float*)d_in[12];
  const float* Wv    = (const float*)d_in[13];
  const float* Wz    = (const float*)d_in[14];
  const float* bz    = (const float*)d_in[15];
  const float* Wf    = (const float*)d_in[16];
  const float* bf_   = (const float*)d_in[17];
  char* ws = (char*)d_ws;

  k_prep<<<dim3(96), dim3(256), 0, stream>>>(W1, ws);
  k_main<<<dim3(2048), dim3(256), 0, stream>>>(inp, b1, g1, be1, Watt1, batt1, g2, be2, Watt2, batt2, ws);
  k_reduce<<<dim3(1), dim3(256), 0, stream>>>(ws);
  k_gather<<<dim3(512), dim3(256), 0, stream>>>(ws);
  k_select<<<dim3(1), dim3(256), 0, stream>>>(ws);
  k_zs<<<dim3(64), dim3(256), 0, stream>>>(inp, W1, b1, g1, be1, Wq, Wk, Wv, ws);
  k_attn<<<dim3(1), dim3(256), 0, stream>>>(ws, (float*)d_out);
  k_wz<<<dim3(128), dim3(256), 0, stream>>>(Wz, bz, Wf, bf_, ws, (float*)d_out);
}

// Round 7
// 2441.198 us; speedup vs baseline: 1.0020x; 1.0020x over previous
//
#include <hip/hip_runtime.h>

// SurvModel: x=relu(BN(in@W1+b1)); h=tanh(BN(x@Watt1+batt1)); s=h@Watt2+batt2;
// A=softmax_N(s); top64 by A desc (stable); zs=x[top]*softmax(A[top]);
// zq/zk/zv=zs@W*; zw=softmax(zq@zk^T)@zv; out=relu(zw.flat@Wz+bz)@Wf+bf.
// Split-fp32 (bf16 hi/lo, 3 MFMAs) keeps scores ~1e-6 accurate (top-64 gap ~1.3e-3).
// R7: 128x128 block, 64x64 per-wave tiles (4x less LDS-read per MFMA than R4 —
// R4 was LDS-BW-bound at 2300cy/iter/CU). A+B dbuf in exactly 64KB -> 2 blk/CU.
// 8 gl_lds/iter, one counted vmcnt(8) (retires only prev stage). Rolled 12x2
// loop, small live state (no R6-style spills). Phase-2 in two 64-row halves.

#define NN   131072
#define DIN  768
#define DH   128
#define DA   32

using f32x4  = __attribute__((ext_vector_type(4))) float;
using bf16x8 = __attribute__((ext_vector_type(8))) __bf16;

// workspace byte offsets
#define WS_S      0            // float[131072] scores
#define WS_PZ8    524288       // float[8192] per-wave-pass sum(exp(s))
#define WS_HIST   557056       // int[4096]
#define WS_MISC   573440       // [0]=Z f32, [2]=cnt int, [3]=bstar int
#define WS_CIDX   573504       // int[512]
#define WS_CS     575552       // float[512]
#define WS_ORDER  577600       // int[64]
#define WS_W      577856       // float[64]
#define WS_ZQ     578112       // float[2048]
#define WS_ZK     586304       // float[2048]
#define WS_ZV     594496       // float[2048]
#define WS_ZW     602688       // float[2048]
#define WS_W1T    610944       // 24*16384 B bf16 hi/lo W1, bank-swizzled layout

__device__ __forceinline__ int s_bin(float s) {
  int b = (int)((s + 6.0f) * (4096.0f / 12.0f));
  return b < 0 ? 0 : (b > 4095 ? 4095 : b);
}

__device__ __forceinline__ void gl_lds16(const void* g, void* l) {
  __builtin_amdgcn_global_load_lds(
      (const __attribute__((address_space(1))) void*)g,
      (__attribute__((address_space(3))) void*)l, 16, 0, 0);
}

// K0: W1 -> bf16 hi/lo, [kc][col][pos], pos = u ^ (col&7) (bank-balanced).
// Also zero hist+misc.
__global__ void k_prep(const float* __restrict__ W1, char* __restrict__ ws) {
  int T = blockIdx.x * 256 + threadIdx.x;       // 0..24575
  if (T < 4112) ((int*)(ws + WS_HIST))[T] = 0;
  int u = T & 7, col = (T >> 3) & 127, kc = T >> 10;
  bf16x8 ov;
  #pragma unroll
  for (int j = 0; j < 8; ++j) {
    int k = (u & 3) * 8 + j;
    float v = W1[(size_t)(kc * 32 + k) * 128 + col];
    __bf16 h = (__bf16)v;
    ov[j] = (u < 4) ? h : (__bf16)(v - (float)h);
  }
  *(bf16x8*)(ws + WS_W1T + (size_t)kc * 16384 + col * 128 + ((u ^ (col & 7)) << 4)) = ov;
}

// ---------------- K1: main GEMM + h + scores ----------------
__global__ __launch_bounds__(256, 2) void k_main(
    const float* __restrict__ inp,
    const float* __restrict__ b1, const float* __restrict__ g1, const float* __restrict__ be1,
    const float* __restrict__ Watt1, const float* __restrict__ batt1,
    const float* __restrict__ g2, const float* __restrict__ be2,
    const float* __restrict__ Watt2, const float* __restrict__ batt2,
    char* __restrict__ ws)
{
  // LDS 64K: [0,16K)A0 [16K,32K)A1 [32K,48K)B0 [48K,64K)B1.
  // Phase 2 reuses: [0,32K) x half-tile, [32K,48K) Watt1.
  __shared__ __align__(16) char lds[65536];
  float* s_out = (float*)(ws + WS_S);
  float* pz8   = (float*)(ws + WS_PZ8);
  int*   hist  = (int*)(ws + WS_HIST);
  const char* w1t = ws + WS_W1T;

  const int t = threadIdx.x;
  const int l = t & 63;
  const int wid = t >> 6;
  const int wr = wid >> 1, wc = wid & 1;   // wave tile: rows wr*64+[0,64), cols wc*64+[0,64)
  const int r15 = l & 15, kg = l >> 4;
  const int blockRow = blockIdx.x * 128;
  const float inv = 1.0f / sqrtf(1.0f + 1e-5f);

  char* Ab0 = lds;            char* Ab1 = lds + 16384;
  char* Bb0 = lds + 32768;    char* Bb1 = lds + 49152;
  char* xh  = lds;
  float* wat = (float*)(lds + 32768);

  // A staging source: thread t, chunk c -> row c*32 + (t>>3), swizzled unit u
  const int arow = t >> 3;
  const int au   = (t & 7) ^ (arow & 7);
  const float* aSrc = inp + (size_t)(blockRow + arow) * DIN + au * 4;
  const char*  bSrc = w1t + t * 16;

  f32x4 acc[4][4];
  #pragma unroll
  for (int i = 0; i < 4; ++i)
    #pragma unroll
    for (int j = 0; j < 4; ++j)
      #pragma unroll
      for (int q = 0; q < 4; ++q) acc[i][j][q] = 0.0f;

#define STAGE(Abuf, Bbuf, kc_) do { \
    _Pragma("unroll") \
    for (int c = 0; c < 4; ++c) \
      gl_lds16(aSrc + (size_t)c * 24576 + (size_t)(kc_) * 32, (Abuf) + c * 4096 + t * 16); \
    _Pragma("unroll") \
    for (int c = 0; c < 4; ++c) \
      gl_lds16(bSrc + (size_t)(kc_) * 16384 + c * 4096, (Bbuf) + c * 4096 + t * 16); \
  } while (0)

#define ITER(Ac, Bc, An, Bn, kc_) do { \
    if ((kc_) < 23) { \
      STAGE(An, Bn, (kc_) + 1); \
      asm volatile("s_waitcnt vmcnt(8)" ::: "memory"); \
    } else { \
      asm volatile("s_waitcnt vmcnt(0)" ::: "memory"); \
    } \
    __builtin_amdgcn_sched_barrier(0); \
    __builtin_amdgcn_s_barrier(); \
    __builtin_amdgcn_sched_barrier(0); \
    bf16x8 ahi0, alo0, ahi1, alo1, ahi2, alo2, ahi3, alo3; \
    _Pragma("unroll") \
    for (int mi = 0; mi < 4; ++mi) { \
      int R = wr * 64 + mi * 16 + r15; \
      const char* base = (Ac) + R * 128; int sw = R & 7; \
      f32x4 x0 = *(const f32x4*)(base + (((2 * kg)     ^ sw) << 4)); \
      f32x4 x1 = *(const f32x4*)(base + (((2 * kg + 1) ^ sw) << 4)); \
      bf16x8 hi, lo; \
      _Pragma("unroll") \
      for (int j = 0; j < 4; ++j) { \
        float v0 = x0[j]; __bf16 h0 = (__bf16)v0; \
        hi[j] = h0; lo[j] = (__bf16)(v0 - (float)h0); \
        float v1 = x1[j]; __bf16 h1 = (__bf16)v1; \
        hi[4 + j] = h1; lo[4 + j] = (__bf16)(v1 - (float)h1); \
      } \
      if (mi == 0) { ahi0 = hi; alo0 = lo; } \
      else if (mi == 1) { ahi1 = hi; alo1 = lo; } \
      else if (mi == 2) { ahi2 = hi; alo2 = lo; } \
      else { ahi3 = hi; alo3 = lo; } \
    } \
    _Pragma("unroll") \
    for (int ni = 0; ni < 4; ++ni) { \
      int C = wc * 64 + ni * 16 + r15; \
      const char* cb = (Bc) + C * 128; int sw = C & 7; \
      bf16x8 bhi = *(const bf16x8*)(cb + ((kg       ^ sw) << 4)); \
      bf16x8 blo = *(const bf16x8*)(cb + (((4 | kg) ^ sw) << 4)); \
      acc[0][ni] = __builtin_amdgcn_mfma_f32_16x16x32_bf16(ahi0, bhi, acc[0][ni], 0, 0, 0); \
      acc[0][ni] = __builtin_amdgcn_mfma_f32_16x16x32_bf16(ahi0, blo, acc[0][ni], 0, 0, 0); \
      acc[0][ni] = __builtin_amdgcn_mfma_f32_16x16x32_bf16(alo0, bhi, acc[0][ni], 0, 0, 0); \
      acc[1][ni] = __builtin_amdgcn_mfma_f32_16x16x32_bf16(ahi1, bhi, acc[1][ni], 0, 0, 0); \
      acc[1][ni] = __builtin_amdgcn_mfma_f32_16x16x32_bf16(ahi1, blo, acc[1][ni], 0, 0, 0); \
      acc[1][ni] = __builtin_amdgcn_mfma_f32_16x16x32_bf16(alo1, bhi, acc[1][ni], 0, 0, 0); \
      acc[2][ni] = __builtin_amdgcn_mfma_f32_16x16x32_bf16(ahi2, bhi, acc[2][ni], 0, 0, 0); \
      acc[2][ni] = __builtin_amdgcn_mfma_f32_16x16x32_bf16(ahi2, blo, acc[2][ni], 0, 0, 0); \
      acc[2][ni] = __builtin_amdgcn_mfma_f32_16x16x32_bf16(alo2, bhi, acc[2][ni], 0, 0, 0); \
      acc[3][ni] = __builtin_amdgcn_mfma_f32_16x16x32_bf16(ahi3, bhi, acc[3][ni], 0, 0, 0); \
      acc[3][ni] = __builtin_amdgcn_mfma_f32_16x16x32_bf16(ahi3, blo, acc[3][ni], 0, 0, 0); \
      acc[3][ni] = __builtin_amdgcn_mfma_f32_16x16x32_bf16(alo3, bhi, acc[3][ni], 0, 0, 0); \
    } \
    __builtin_amdgcn_sched_barrier(0); \
    __builtin_amdgcn_s_barrier(); \
    __builtin_amdgcn_sched_barrier(0); \
  } while (0)

  STAGE(Ab0, Bb0, 0);
  for (int kc2 = 0; kc2 < 12; ++kc2) {          // rolled: no unroll-bloat spills
    ITER(Ab0, Bb0, Ab1, Bb1, kc2 * 2);
    ITER(Ab1, Bb1, Ab0, Bb0, kc2 * 2 + 1);
  }
#undef ITER
#undef STAGE

  __syncthreads();
  // load Watt1 into [32K,48K)
  #pragma unroll
  for (int c = 0; c < 4; ++c)
    gl_lds16(Watt1 + c * 1024 + t * 4, (char*)wat + c * 4096 + t * 16);
  asm volatile("s_waitcnt vmcnt(0)" ::: "memory");
  __syncthreads();

  // phase 2 in two 64-row halves: BN+relu -> x-half; h/tanh/score per half
  const int row = t >> 2, q4 = t & 3;          // 64 rows, 4 threads/row, 8 a-dims each
  const int rsw = (row & 31) << 4;
  for (int pass = 0; pass < 2; ++pass) {
    if (wr == pass) {
      #pragma unroll
      for (int ni = 0; ni < 4; ++ni) {
        int col = wc * 64 + ni * 16 + r15;
        float b1c = b1[col], s1c = g1[col] * inv, be1c = be1[col];
        #pragma unroll
        for (int mi = 0; mi < 4; ++mi) {
          #pragma unroll
          for (int q = 0; q < 4; ++q) {
            int rloc = mi * 16 + kg * 4 + q;
            float xv = fmaxf((acc[mi][ni][q] + b1c) * s1c + be1c, 0.0f);
            *(float*)(xh + rloc * 512 + ((col * 4) ^ ((rloc & 31) << 4))) = xv;
          }
        }
      }
    }
    __syncthreads();
    float hacc[8];
    #pragma unroll
    for (int a = 0; a < 8; ++a) hacc[a] = 0.0f;
    const char* xrow = xh + row * 512;
    const float* watt = wat + q4 * 8;
    for (int cb = 0; cb < 128; cb += 4) {
      f32x4 xv = *(const f32x4*)(xrow + ((cb * 4) ^ rsw));
      #pragma unroll
      for (int u = 0; u < 4; ++u) {
        const float* wrow = watt + (cb + u) * 32;
        f32x4 w0 = *(const f32x4*)(wrow);
        f32x4 w1 = *(const f32x4*)(wrow + 4);
        float xs = xv[u];
        #pragma unroll
        for (int q = 0; q < 4; ++q) {
          hacc[q]     += xs * w0[q];
          hacc[4 + q] += xs * w1[q];
        }
      }
    }
    float partial = 0.0f;
    #pragma unroll
    for (int a = 0; a < 8; ++a) {
      int ai = q4 * 8 + a;
      float hv = tanhf((hacc[a] + batt1[ai]) * (g2[ai] * inv) + be2[ai]);
      partial += hv * Watt2[ai];
    }
    partial += __shfl_xor(partial, 1, 64);
    partial += __shfl_xor(partial, 2, 64);
    float ev = 0.0f;
    if (q4 == 0) {
      float sv = partial + batt2[0];
      s_out[blockRow + pass * 64 + row] = sv;
      atomicAdd(&hist[s_bin(sv)], 1);
      ev = expf(sv);
    }
    #pragma unroll
    for (int off = 32; off >= 1; off >>= 1) ev += __shfl_xor(ev, off, 64);
    if (l == 0) pz8[blockIdx.x * 8 + pass * 4 + wid] = ev;
    __syncthreads();
  }
}

// ---------------- K2: Z reduce + histogram threshold ----------------
__global__ void k_reduce(char* __restrict__ ws) {
  float* pz8 = (float*)(ws + WS_PZ8);
  int* hist = (int*)(ws + WS_HIST);
  float* miscf = (float*)(ws + WS_MISC);
  int* misci = (int*)(ws + WS_MISC);
  const int t = threadIdx.x;
  __shared__ float red[256];
  __shared__ int csum[256];
  float z = 0.0f;
  for (int i = t; i < 8192; i += 256) z += pz8[i];
  red[t] = z;
  int c = 0;
  #pragma unroll
  for (int u = 0; u < 16; ++u) c += hist[t * 16 + u];
  csum[t] = c;
  __syncthreads();
  for (int off = 128; off >= 1; off >>= 1) {
    if (t < off) red[t] += red[t + off];
    __syncthreads();
  }
  if (t == 0) {
    miscf[0] = red[0];
    int cum = 0, bstar = 0;
    for (int ch = 255; ch >= 0; --ch) {
      if (cum + csum[ch] >= 64) {
        for (int b = ch * 16 + 15; b >= ch * 16; --b) {
          cum += hist[b];
          if (cum >= 64) { bstar = b; break; }
        }
        break;
      }
      cum += csum[ch];
    }
    misci[3] = bstar;
    misci[2] = 0;
  }
}

// ---------------- K3: gather candidates ----------------
__global__ void k_gather(char* __restrict__ ws) {
  const int i = blockIdx.x * 256 + threadIdx.x;
  float* s_out = (float*)(ws + WS_S);
  int* misci = (int*)(ws + WS_MISC);
  int* cidx = (int*)(ws + WS_CIDX);
  float* cs = (float*)(ws + WS_CS);
  float s = s_out[i];
  if (s_bin(s) >= misci[3]) {
    int pos = atomicAdd(&misci[2], 1);
    if (pos < 512) { cidx[pos] = i; cs[pos] = s; }
  }
}

// ---------------- K4: sort candidates, top-64 order + weights ----------------
__global__ void k_select(char* __restrict__ ws) {
  const int t = threadIdx.x;
  float* s_out = (float*)(ws + WS_S);
  int* misci = (int*)(ws + WS_MISC);
  float* miscf = (float*)(ws + WS_MISC);
  int* cidx = (int*)(ws + WS_CIDX);
  float* cs = (float*)(ws + WS_CS);
  int* order = (int*)(ws + WS_ORDER);
  float* wsel = (float*)(ws + WS_W);
  __shared__ unsigned long long keys[512];
  __shared__ float aLds[64];
  int cnt = misci[2]; if (cnt > 512) cnt = 512;
  for (int i = t; i < 512; i += 256) {
    unsigned long long kkey = 0xFFFFFFFFFFFFFFFFull;
    if (i < cnt) {
      unsigned u = __float_as_uint(cs[i]);
      u = (u & 0x80000000u) ? ~u : (u | 0x80000000u);  // ascending map
      unsigned du = ~u;                                 // descending by s
      kkey = ((unsigned long long)du << 32) | (unsigned)cidx[i];  // tie: idx asc
    }
    keys[i] = kkey;
  }
  __syncthreads();
  for (int k = 2; k <= 512; k <<= 1) {
    for (int j = k >> 1; j > 0; j >>= 1) {
      for (int i = t; i < 512; i += 256) {
        int ixj = i ^ j;
        if (ixj > i) {
          bool up = ((i & k) == 0);
          unsigned long long a = keys[i], b2 = keys[ixj];
          if (up ? (a > b2) : (a < b2)) { keys[i] = b2; keys[ixj] = a; }
        }
      }
      __syncthreads();
    }
  }
  float Z = miscf[0];
  if (t < 64) {
    int idx = (int)(keys[t] & 0xFFFFFFFFull);
    order[t] = idx;
    aLds[t] = expf(s_out[idx]) / Z;
  }
  __syncthreads();
  if (t < 64) {
    float m = aLds[0];                // sorted desc -> max
    float e = expf(aLds[t] - m);
    float sum = e;
    #pragma unroll
    for (int off = 32; off >= 1; off >>= 1) sum += __shfl_xor(sum, off, 64);
    wsel[t] = e / sum;
  }
}

// ---------------- K5: recompute x for top-64, zs, zq/zk/zv ----------------
__global__ void k_zs(const float* __restrict__ inp, const float* __restrict__ W1,
                     const float* __restrict__ b1, const float* __restrict__ g1, const float* __restrict__ be1,
                     const float* __restrict__ Wq, const float* __restrict__ Wk, const float* __restrict__ Wv,
                     char* __restrict__ ws)
{
  const int t = threadIdx.x, b = blockIdx.x;
  int* order = (int*)(ws + WS_ORDER);
  float* wsel = (float*)(ws + WS_W);
  float* zq = (float*)(ws + WS_ZQ);
  float* zk = (float*)(ws + WS_ZK);
  float* zv = (float*)(ws + WS_ZV);
  __shared__ float rowS[768];
  __shared__ float zsS[128];
  const float inv = 1.0f / sqrtf(1.0f + 1e-5f);
  int r = order[b];
  float wgt = wsel[b];
  for (int i = t; i < 768; i += 256) rowS[i] = inp[(size_t)r * 768 + i];
  __syncthreads();
  if (t < 128) {
    float d = 0.0f;
    for (int k = 0; k < 768; ++k) d += rowS[k] * W1[(size_t)k * 128 + t];
    float x = fmaxf((d + b1[t]) * (g1[t] * inv) + be1[t], 0.0f);
    zsS[t] = x * wgt;
  }
  __syncthreads();
  if (t < 96) {
    int which = t >> 5, a = t & 31;
    const float* W = (which == 0) ? Wq : ((which == 1) ? Wk : Wv);
    float d = 0.0f;
    for (int c = 0; c < 128; ++c) d += zsS[c] * W[c * 32 + a];
    float* dst = (which == 0) ? zq : ((which == 1) ? zk : zv);
    dst[b * 32 + a] = d;
  }
}

// ---------------- K6a: 64x64 attention (also zeroes d_out for K6b atomics) ----
__global__ void k_attn(char* __restrict__ ws, float* __restrict__ out) {
  const int t = threadIdx.x;
  if (t == 0) out[0] = 0.0f;
  float* zq = (float*)(ws + WS_ZQ);
  float* zk = (float*)(ws + WS_ZK);
  float* zv = (float*)(ws + WS_ZV);
  float* zw = (float*)(ws + WS_ZW);
  __shared__ float q[2048], kk[2048], v[2048], P[4096];
  for (int i = t; i < 2048; i += 256) { q[i] = zq[i]; kk[i] = zk[i]; v[i] = zv[i]; }
  __syncthreads();
  for (int o = t; o < 4096; o += 256) {
    int i = o >> 6, j = o & 63;
    float d = 0.0f;
    for (int a = 0; a < 32; ++a) d += q[i * 32 + a] * kk[j * 32 + a];
    P[o] = d;
  }
  __syncthreads();
  if (t < 64) {
    float m = -1e30f;
    for (int j = 0; j < 64; ++j) m = fmaxf(m, P[t * 64 + j]);
    float sum = 0.0f;
    for (int j = 0; j < 64; ++j) { float e = expf(P[t * 64 + j] - m); P[t * 64 + j] = e; sum += e; }
    float rs = 1.0f / sum;
    for (int j = 0; j < 64; ++j) P[t * 64 + j] *= rs;
  }
  __syncthreads();
  for (int o = t; o < 2048; o += 256) {
    int i = o >> 5, a = o & 31;
    float d = 0.0f;
    for (int j = 0; j < 64; ++j) d += P[i * 64 + j] * v[j * 32 + a];
    zw[o] = d;
  }
}

// ---------------- K6b: zw.flat @ Wz + bz, relu, dot Wf, atomic out -----------
__global__ void k_wz(const float* __restrict__ Wz, const float* __restrict__ bz,
                     const float* __restrict__ Wf, const float* __restrict__ bf_,
                     char* __restrict__ ws, float* __restrict__ out) {
  const int t = threadIdx.x, j = blockIdx.x;
  float* zw = (float*)(ws + WS_ZW);
  __shared__ float red[256];
  float p = 0.0f;
  for (int i2 = t; i2 < 2048; i2 += 256) p += zw[i2] * Wz[(size_t)i2 * 128 + j];
  red[t] = p; __syncthreads();
  for (int off = 128; off >= 1; off >>= 1) {
    if (t < off) red[t] += red[t + off];
    __syncthreads();
  }
  if (t == 0) {
    float o = fmaxf(red[0] + bz[j], 0.0f);
    float contrib = o * Wf[j] + (j == 0 ? bf_[0] : 0.0f);
    atomicAdd(out, contrib);
  }
}

extern "C" void kernel_launch(void* const* d_in, const int* in_sizes, int n_in,
                              void* d_out, int out_size, void* d_ws, size_t ws_size,
                              hipStream_t stream) {
  const float* inp   = (const float*)d_in[0];
  const float* W1    = (const float*)d_in[1];
  const float* b1    = (const float*)d_in[2];
  const float* g1    = (const float*)d_in[3];
  const float* be1   = (const float*)d_in[4];
  const float* Watt1 = (const float*)d_in[5];
  const float* batt1 = (const float*)d_in[6];
  const float* g2    = (const float*)d_in[7];
  const float* be2   = (const float*)d_in[8];
  const float* Watt2 = (const float*)d_in[9];
  const float* batt2 = (const float*)d_in[10];
  const float* Wq    = (const float*)d_in[11];
  const float* Wk    = (const float*)d_in[12];
  const float* Wv    = (const float*)d_in[13];
  const float* Wz    = (const float*)d_in[14];
  const float* bz    = (const float*)d_in[15];
  const float* Wf    = (const float*)d_in[16];
  const float* bf_   = (const float*)d_in[17];
  char* ws = (char*)d_ws;

  k_prep<<<dim3(96), dim3(256), 0, stream>>>(W1, ws);
  k_main<<<dim3(1024), dim3(256), 0, stream>>>(inp, b1, g1, be1, Watt1, batt1, g2, be2, Watt2, batt2, ws);
  k_reduce<<<dim3(1), dim3(256), 0, stream>>>(ws);
  k_gather<<<dim3(512), dim3(256), 0, stream>>>(ws);
  k_select<<<dim3(1), dim3(256), 0, stream>>>(ws);
  k_zs<<<dim3(64), dim3(256), 0, stream>>>(inp, W1, b1, g1, be1, Wq, Wk, Wv, ws);
  k_attn<<<dim3(1), dim3(256), 0, stream>>>(ws, (float*)d_out);
  k_wz<<<dim3(128), dim3(256), 0, stream>>>(Wz, bz, Wf, bf_, ws, (float*)d_out);
}

// Round 8
// 388.613 us; speedup vs baseline: 6.2941x; 6.2818x over previous
//
#include <hip/hip_runtime.h>

// SurvModel: x=relu(BN(in@W1+b1)); h=tanh(BN(x@Watt1+batt1)); s=h@Watt2+batt2;
// A=softmax_N(s); top64 by A desc (stable); zs=x[top]*softmax(A[top]);
// zq/zk/zv=zs@W*; zw=softmax(zq@zk^T)@zv; out=relu(zw.flat@Wz+bz)@Wf+bf.
// R8: plain-bf16 GEMM (scores approx, err ~5e-3) + margin threshold (0.07) +
// EXACT fp32 rescore of ~70 candidates -> selection exactness without split-fp32.
// k-loop: barrier-free, LDS-free; per-wave 16 rows; A depth-4 reg ring (96KB/CU
// in flight > BDP); B frags direct from L2-resident W1Thi. Rolled loop
// (#pragma unroll 1), bounded live state (~140 VGPR) -- no R6/R7 hoist-spills.

#define NN   131072
#define DIN  768
#define DH   128
#define DA   32

using f32x4  = __attribute__((ext_vector_type(4))) float;
using bf16x8 = __attribute__((ext_vector_type(8))) __bf16;

// workspace byte offsets
#define WS_S      0            // float[131072] approx scores
#define WS_PZ8    524288       // float[8192] per-wave sum(exp(s))
#define WS_HIST   557056       // int[4096]
#define WS_MISC   573440       // [0]=Z f32, [2]=cnt int, [3]=bstar int
#define WS_CIDX   573504       // int[512]
#define WS_CS     575552       // float[512] (approx from gather, exact after k_exact)
#define WS_ORDER  577600       // int[64]
#define WS_W      577856       // float[64]
#define WS_ZQ     578112       // float[2048]
#define WS_ZK     586304       // float[2048]
#define WS_ZV     594496       // float[2048]
#define WS_ZW     602688       // float[2048]
#define WS_W1T    610944       // 24*8192 B bf16(hi) W1, [kc][col][kg] frag layout

__device__ __forceinline__ int s_bin(float s) {
  int b = (int)((s + 6.0f) * (4096.0f / 12.0f));
  return b < 0 ? 0 : (b > 4095 ? 4095 : b);
}

// K0: W1 -> bf16, [kc][col][kg]: 16B unit (kc,col,kg) = bf16(W1[kc*32+kg*8+j][col]).
// Also zero hist+misc.
__global__ void k_prep(const float* __restrict__ W1, char* __restrict__ ws) {
  int T = blockIdx.x * 256 + threadIdx.x;       // grid 48*256 = 12288
  if (T < 4112) ((int*)(ws + WS_HIST))[T] = 0;
  int kg = T & 3, col = (T >> 2) & 127, kc = T >> 9;
  bf16x8 ov;
  #pragma unroll
  for (int j = 0; j < 8; ++j)
    ov[j] = (__bf16)W1[(size_t)(kc * 32 + kg * 8 + j) * 128 + col];
  *(bf16x8*)(ws + WS_W1T + (size_t)kc * 8192 + col * 64 + kg * 16) = ov;
}

// ---------------- K1: main GEMM (plain bf16) + h + approx scores ----------------
__global__ __launch_bounds__(256, 3) void k_main(
    const float* __restrict__ inp,
    const float* __restrict__ b1, const float* __restrict__ g1, const float* __restrict__ be1,
    const float* __restrict__ Watt1, const float* __restrict__ batt1,
    const float* __restrict__ g2, const float* __restrict__ be2,
    const float* __restrict__ Watt2, const float* __restrict__ batt2,
    char* __restrict__ ws)
{
  // LDS 16K: xh bf16 [64 rows][256B], 16B-unit XOR-swizzled (phase 2 only)
  __shared__ __align__(16) char lds[16384];
  float* s_out = (float*)(ws + WS_S);
  float* pz8   = (float*)(ws + WS_PZ8);
  int*   hist  = (int*)(ws + WS_HIST);
  const char* w1t = ws + WS_W1T;

  const int t = threadIdx.x;
  const int l = t & 63;
  const int wid = t >> 6;
  const int r15 = l & 15, kg = l >> 4;
  const int blockRow = blockIdx.x * 64;
  const float inv = 1.0f / sqrtf(1.0f + 1e-5f);

  // A: wave rows blockRow + wid*16 + r15; per kc 8 floats at kc*32 + kg*8
  const float* aP = inp + (size_t)(blockRow + wid * 16 + r15) * DIN + kg * 8;
  // B frag lane base: col r15 (+ni*16 -> +ni*1024B), unit kg
  const char* bP = w1t + r15 * 64 + kg * 16;

  f32x4 acc[8];
  #pragma unroll
  for (int i = 0; i < 8; ++i)
    #pragma unroll
    for (int q = 0; q < 4; ++q) acc[i][q] = 0.0f;

#define LOADB(s, kc_) do { const char* bb_ = bP + (size_t)(kc_) * 8192; \
    s##0 = *(const bf16x8*)(bb_);          s##1 = *(const bf16x8*)(bb_ + 1024); \
    s##2 = *(const bf16x8*)(bb_ + 2048);   s##3 = *(const bf16x8*)(bb_ + 3072); \
    s##4 = *(const bf16x8*)(bb_ + 4096);   s##5 = *(const bf16x8*)(bb_ + 5120); \
    s##6 = *(const bf16x8*)(bb_ + 6144);   s##7 = *(const bf16x8*)(bb_ + 7168); \
  } while (0)
#define LOADA(x0, x1, kc_) do { const float* ap_ = aP + (kc_) * 32; \
    x0 = *(const f32x4*)(ap_); x1 = *(const f32x4*)(ap_ + 4); } while (0)
  // body: convert A(kc) [pair pa], issue B(kc+1)->bn, A(kc+4)->pa, 8 MFMAs on bs
#define BODY(pa0, pa1, bs, bn, kcb, kca) do { \
    bf16x8 ah_; \
    _Pragma("unroll") \
    for (int j_ = 0; j_ < 4; ++j_) { \
      ah_[j_]     = (__bf16)pa0[j_]; \
      ah_[4 + j_] = (__bf16)pa1[j_]; \
    } \
    LOADB(bn, kcb); \
    LOADA(pa0, pa1, kca); \
    acc[0] = __builtin_amdgcn_mfma_f32_16x16x32_bf16(ah_, bs##0, acc[0], 0, 0, 0); \
    acc[1] = __builtin_amdgcn_mfma_f32_16x16x32_bf16(ah_, bs##1, acc[1], 0, 0, 0); \
    acc[2] = __builtin_amdgcn_mfma_f32_16x16x32_bf16(ah_, bs##2, acc[2], 0, 0, 0); \
    acc[3] = __builtin_amdgcn_mfma_f32_16x16x32_bf16(ah_, bs##3, acc[3], 0, 0, 0); \
    acc[4] = __builtin_amdgcn_mfma_f32_16x16x32_bf16(ah_, bs##4, acc[4], 0, 0, 0); \
    acc[5] = __builtin_amdgcn_mfma_f32_16x16x32_bf16(ah_, bs##5, acc[5], 0, 0, 0); \
    acc[6] = __builtin_amdgcn_mfma_f32_16x16x32_bf16(ah_, bs##6, acc[6], 0, 0, 0); \
    acc[7] = __builtin_amdgcn_mfma_f32_16x16x32_bf16(ah_, bs##7, acc[7], 0, 0, 0); \
  } while (0)

  // A ring depth 4 (pairs q0..q3), B ping-pong (bc/bn)
  f32x4 q00, q01, q10, q11, q20, q21, q30, q31;
  bf16x8 bc0, bc1, bc2, bc3, bc4, bc5, bc6, bc7;
  bf16x8 bn0, bn1, bn2, bn3, bn4, bn5, bn6, bn7;
  LOADA(q00, q01, 0); LOADA(q10, q11, 1); LOADA(q20, q21, 2); LOADA(q30, q31, 3);
  LOADB(bc, 0);

  #pragma unroll 1
  for (int kc4 = 0; kc4 < 6; ++kc4) {
    const int kc = kc4 * 4;
    const int p4 = (kc + 4 < 24) ? kc + 4 : 23;   // A prefetch clamp
    const int p5 = (kc + 5 < 24) ? kc + 5 : 23;
    const int p6 = (kc + 6 < 24) ? kc + 6 : 23;
    const int p7 = (kc + 7 < 24) ? kc + 7 : 23;
    const int b4 = (kc + 4 < 24) ? kc + 4 : 23;   // B prefetch clamp (last body)
    BODY(q00, q01, bc, bn, kc + 1, p4);
    BODY(q10, q11, bn, bc, kc + 2, p5);
    BODY(q20, q21, bc, bn, kc + 3, p6);
    BODY(q30, q31, bn, bc, b4,     p7);
  }
#undef BODY
#undef LOADA
#undef LOADB

  // epilogue: BN + relu -> xh bf16 (row local 0..63, swizzled 16B units)
  #pragma unroll
  for (int ni = 0; ni < 8; ++ni) {
    int col = ni * 16 + r15;
    float b1c = b1[col], s1c = g1[col] * inv, be1c = be1[col];
    #pragma unroll
    for (int q = 0; q < 4; ++q) {
      int row = wid * 16 + kg * 4 + q;
      float xv = fmaxf((acc[ni][q] + b1c) * s1c + be1c, 0.0f);
      *(__bf16*)(lds + row * 256 + (((col >> 3) ^ (row & 15)) << 4) + (col & 7) * 2) =
          (__bf16)xv;
    }
  }
  __syncthreads();

  // h = tanh(BN(x@Watt1)); s = h@Watt2 + batt2; Z partials; histogram
  {
    const int row = t >> 2, q4 = t & 3;     // 64 rows, 4 threads/row, 8 a-dims each
    float hacc[8];
    #pragma unroll
    for (int a = 0; a < 8; ++a) hacc[a] = 0.0f;
    const char* xrow = lds + row * 256;
    const int rsw = row & 15;
    for (int ub = 0; ub < 16; ++ub) {
      bf16x8 xv = *(const bf16x8*)(xrow + (((ub) ^ rsw) << 4));
      #pragma unroll
      for (int j = 0; j < 8; ++j) {
        const float* wrow = Watt1 + (ub * 8 + j) * 32 + q4 * 8;
        f32x4 w0 = *(const f32x4*)(wrow);
        f32x4 w1 = *(const f32x4*)(wrow + 4);
        float xs = (float)xv[j];
        #pragma unroll
        for (int q = 0; q < 4; ++q) {
          hacc[q]     += xs * w0[q];
          hacc[4 + q] += xs * w1[q];
        }
      }
    }
    float partial = 0.0f;
    #pragma unroll
    for (int a = 0; a < 8; ++a) {
      int ai = q4 * 8 + a;
      float hv = tanhf((hacc[a] + batt1[ai]) * (g2[ai] * inv) + be2[ai]);
      partial += hv * Watt2[ai];
    }
    partial += __shfl_xor(partial, 1, 64);
    partial += __shfl_xor(partial, 2, 64);
    float ev = 0.0f;
    if (q4 == 0) {
      float sv = partial + batt2[0];
      s_out[blockRow + row] = sv;
      atomicAdd(&hist[s_bin(sv)], 1);
      ev = expf(sv);
    }
    #pragma unroll
    for (int off = 32; off >= 1; off >>= 1) ev += __shfl_xor(ev, off, 64);
    if (l == 0) pz8[blockIdx.x * 4 + wid] = ev;
  }
}

// ---------------- K2: Z reduce + histogram threshold (with margin) ----------------
__global__ void k_reduce(char* __restrict__ ws) {
  float* pz8 = (float*)(ws + WS_PZ8);
  int* hist = (int*)(ws + WS_HIST);
  float* miscf = (float*)(ws + WS_MISC);
  int* misci = (int*)(ws + WS_MISC);
  const int t = threadIdx.x;
  __shared__ float red[256];
  __shared__ int csum[256];
  float z = 0.0f;
  for (int i = t; i < 8192; i += 256) z += pz8[i];
  red[t] = z;
  int c = 0;
  #pragma unroll
  for (int u = 0; u < 16; ++u) c += hist[t * 16 + u];
  csum[t] = c;
  __syncthreads();
  for (int off = 128; off >= 1; off >>= 1) {
    if (t < off) red[t] += red[t + off];
    __syncthreads();
  }
  if (t == 0) {
    miscf[0] = red[0];
    int cum = 0, bstar = 0;
    for (int ch = 255; ch >= 0; --ch) {
      if (cum + csum[ch] >= 64) {
        for (int b = ch * 16 + 15; b >= ch * 16; --b) {
          cum += hist[b];
          if (cum >= 64) { bstar = b; break; }
        }
        break;
      }
      cum += csum[ch];
    }
    // margin: 24 bins = 0.07 in s, >> bf16-GEMM score error ~5e-3
    misci[3] = (bstar > 24) ? bstar - 24 : 0;
    misci[2] = 0;
  }
}

// ---------------- K3: gather candidates (approx s >= margin threshold) --------
__global__ void k_gather(char* __restrict__ ws) {
  const int i = blockIdx.x * 256 + threadIdx.x;
  float* s_out = (float*)(ws + WS_S);
  int* misci = (int*)(ws + WS_MISC);
  int* cidx = (int*)(ws + WS_CIDX);
  float* cs = (float*)(ws + WS_CS);
  float s = s_out[i];
  if (s_bin(s) >= misci[3]) {
    int pos = atomicAdd(&misci[2], 1);
    if (pos < 512) { cidx[pos] = i; cs[pos] = s; }
  }
}

// ---------------- K3b: EXACT fp32 rescore of candidates ----------------------
__global__ void k_exact(const float* __restrict__ inp, const float* __restrict__ W1,
                        const float* __restrict__ b1, const float* __restrict__ g1,
                        const float* __restrict__ be1,
                        const float* __restrict__ Watt1, const float* __restrict__ batt1,
                        const float* __restrict__ g2, const float* __restrict__ be2,
                        const float* __restrict__ Watt2, const float* __restrict__ batt2,
                        char* __restrict__ ws)
{
  int* misci = (int*)(ws + WS_MISC);
  int* cidx = (int*)(ws + WS_CIDX);
  float* cs = (float*)(ws + WS_CS);
  const int b = blockIdx.x, t = threadIdx.x;
  int cnt = misci[2]; if (cnt > 512) cnt = 512;
  if (b >= cnt) return;
  __shared__ float rowS[768];
  __shared__ float xS[128];
  __shared__ float hS[32];
  const float inv = 1.0f / sqrtf(1.0f + 1e-5f);
  const int r = cidx[b];
  for (int i = t; i < 768; i += 256) rowS[i] = inp[(size_t)r * 768 + i];
  __syncthreads();
  if (t < 128) {
    float d = 0.0f;
    for (int k = 0; k < 768; ++k) d += rowS[k] * W1[(size_t)k * 128 + t];
    xS[t] = fmaxf((d + b1[t]) * (g1[t] * inv) + be1[t], 0.0f);
  }
  __syncthreads();
  if (t < 32) {
    float d = 0.0f;
    for (int c = 0; c < 128; ++c) d += xS[c] * Watt1[c * 32 + t];
    hS[t] = tanhf((d + batt1[t]) * (g2[t] * inv) + be2[t]);
  }
  __syncthreads();
  if (t == 0) {
    float s = 0.0f;
    for (int a = 0; a < 32; ++a) s += hS[a] * Watt2[a];
    cs[b] = s + batt2[0];
  }
}

// ---------------- K4: sort candidates by EXACT s, top-64 + weights ------------
__global__ void k_select(char* __restrict__ ws) {
  const int t = threadIdx.x;
  int* misci = (int*)(ws + WS_MISC);
  float* miscf = (float*)(ws + WS_MISC);
  int* cidx = (int*)(ws + WS_CIDX);
  float* cs = (float*)(ws + WS_CS);
  int* order = (int*)(ws + WS_ORDER);
  float* wsel = (float*)(ws + WS_W);
  __shared__ unsigned long long keys[512];
  __shared__ float aLds[64];
  int cnt = misci[2]; if (cnt > 512) cnt = 512;
  for (int i = t; i < 512; i += 256) {
    unsigned long long kkey = 0xFFFFFFFFFFFFFFFFull;
    if (i < cnt) {
      unsigned u = __float_as_uint(cs[i]);
      u = (u & 0x80000000u) ? ~u : (u | 0x80000000u);  // ascending map
      unsigned du = ~u;                                 // descending by s
      kkey = ((unsigned long long)du << 32) | (unsigned)cidx[i];  // tie: idx asc
    }
    keys[i] = kkey;
  }
  __syncthreads();
  for (int k = 2; k <= 512; k <<= 1) {
    for (int j = k >> 1; j > 0; j >>= 1) {
      for (int i = t; i < 512; i += 256) {
        int ixj = i ^ j;
        if (ixj > i) {
          bool up = ((i & k) == 0);
          unsigned long long a = keys[i], b2 = keys[ixj];
          if (up ? (a > b2) : (a < b2)) { keys[i] = b2; keys[ixj] = a; }
        }
      }
      __syncthreads();
    }
  }
  float Z = miscf[0];
  if (t < 64) {
    unsigned du = (unsigned)(keys[t] >> 32);
    unsigned m = ~du;                       // undo descending map
    float sx = (m & 0x80000000u) ? __uint_as_float(m & 0x7fffffffu)
                                 : __uint_as_float(~m);
    order[t] = (int)(keys[t] & 0xFFFFFFFFull);
    aLds[t] = expf(sx) / Z;                 // exact s, approx Z (insensitive)
  }
  __syncthreads();
  if (t < 64) {
    float m = aLds[0];                      // sorted desc -> max
    float e = expf(aLds[t] - m);
    float sum = e;
    #pragma unroll
    for (int off = 32; off >= 1; off >>= 1) sum += __shfl_xor(sum, off, 64);
    wsel[t] = e / sum;
  }
}

// ---------------- K5: recompute x for top-64, zs, zq/zk/zv ----------------
__global__ void k_zs(const float* __restrict__ inp, const float* __restrict__ W1,
                     const float* __restrict__ b1, const float* __restrict__ g1, const float* __restrict__ be1,
                     const float* __restrict__ Wq, const float* __restrict__ Wk, const float* __restrict__ Wv,
                     char* __restrict__ ws)
{
  const int t = threadIdx.x, b = blockIdx.x;
  int* order = (int*)(ws + WS_ORDER);
  float* wsel = (float*)(ws + WS_W);
  float* zq = (float*)(ws + WS_ZQ);
  float* zk = (float*)(ws + WS_ZK);
  float* zv = (float*)(ws + WS_ZV);
  __shared__ float rowS[768];
  __shared__ float zsS[128];
  const float inv = 1.0f / sqrtf(1.0f + 1e-5f);
  int r = order[b];
  float wgt = wsel[b];
  for (int i = t; i < 768; i += 256) rowS[i] = inp[(size_t)r * 768 + i];
  __syncthreads();
  if (t < 128) {
    float d = 0.0f;
    for (int k = 0; k < 768; ++k) d += rowS[k] * W1[(size_t)k * 128 + t];
    float x = fmaxf((d + b1[t]) * (g1[t] * inv) + be1[t], 0.0f);
    zsS[t] = x * wgt;
  }
  __syncthreads();
  if (t < 96) {
    int which = t >> 5, a = t & 31;
    const float* W = (which == 0) ? Wq : ((which == 1) ? Wk : Wv);
    float d = 0.0f;
    for (int c = 0; c < 128; ++c) d += zsS[c] * W[c * 32 + a];
    float* dst = (which == 0) ? zq : ((which == 1) ? zk : zv);
    dst[b * 32 + a] = d;
  }
}

// ---------------- K6a: 64x64 attention (also zeroes d_out for K6b atomics) ----
__global__ void k_attn(char* __restrict__ ws, float* __restrict__ out) {
  const int t = threadIdx.x;
  if (t == 0) out[0] = 0.0f;
  float* zq = (float*)(ws + WS_ZQ);
  float* zk = (float*)(ws + WS_ZK);
  float* zv = (float*)(ws + WS_ZV);
  float* zw = (float*)(ws + WS_ZW);
  __shared__ float q[2048], kk[2048], v[2048], P[4096];
  for (int i = t; i < 2048; i += 256) { q[i] = zq[i]; kk[i] = zk[i]; v[i] = zv[i]; }
  __syncthreads();
  for (int o = t; o < 4096; o += 256) {
    int i = o >> 6, j = o & 63;
    float d = 0.0f;
    for (int a = 0; a < 32; ++a) d += q[i * 32 + a] * kk[j * 32 + a];
    P[o] = d;
  }
  __syncthreads();
  if (t < 64) {
    float m = -1e30f;
    for (int j = 0; j < 64; ++j) m = fmaxf(m, P[t * 64 + j]);
    float sum = 0.0f;
    for (int j = 0; j < 64; ++j) { float e = expf(P[t * 64 + j] - m); P[t * 64 + j] = e; sum += e; }
    float rs = 1.0f / sum;
    for (int j = 0; j < 64; ++j) P[t * 64 + j] *= rs;
  }
  __syncthreads();
  for (int o = t; o < 2048; o += 256) {
    int i = o >> 5, a = o & 31;
    float d = 0.0f;
    for (int j = 0; j < 64; ++j) d += P[i * 64 + j] * v[j * 32 + a];
    zw[o] = d;
  }
}

// ---------------- K6b: zw.flat @ Wz + bz, relu, dot Wf, atomic out -----------
__global__ void k_wz(const float* __restrict__ Wz, const float* __restrict__ bz,
                     const float* __restrict__ Wf, const float* __restrict__ bf_,
                     char* __restrict__ ws, float* __restrict__ out) {
  const int t = threadIdx.x, j = blockIdx.x;
  float* zw = (float*)(ws + WS_ZW);
  __shared__ float red[256];
  float p = 0.0f;
  for (int i2 = t; i2 < 2048; i2 += 256) p += zw[i2] * Wz[(size_t)i2 * 128 + j];
  red[t] = p; __syncthreads();
  for (int off = 128; off >= 1; off >>= 1) {
    if (t < off) red[t] += red[t + off];
    __syncthreads();
  }
  if (t == 0) {
    float o = fmaxf(red[0] + bz[j], 0.0f);
    float contrib = o * Wf[j] + (j == 0 ? bf_[0] : 0.0f);
    atomicAdd(out, contrib);
  }
}

extern "C" void kernel_launch(void* const* d_in, const int* in_sizes, int n_in,
                              void* d_out, int out_size, void* d_ws, size_t ws_size,
                              hipStream_t stream) {
  const float* inp   = (const float*)d_in[0];
  const float* W1    = (const float*)d_in[1];
  const float* b1    = (const float*)d_in[2];
  const float* g1    = (const float*)d_in[3];
  const float* be1   = (const float*)d_in[4];
  const float* Watt1 = (const float*)d_in[5];
  const float* batt1 = (const float*)d_in[6];
  const float* g2    = (const float*)d_in[7];
  const float* be2   = (const float*)d_in[8];
  const float* Watt2 = (const float*)d_in[9];
  const float* batt2 = (const float*)d_in[10];
  const float* Wq    = (const float*)d_in[11];
  const float* Wk    = (const float*)d_in[12];
  const float* Wv    = (const float*)d_in[13];
  const float* Wz    = (const float*)d_in[14];
  const float* bz    = (const float*)d_in[15];
  const float* Wf    = (const float*)d_in[16];
  const float* bf_   = (const float*)d_in[17];
  char* ws = (char*)d_ws;

  k_prep<<<dim3(48), dim3(256), 0, stream>>>(W1, ws);
  k_main<<<dim3(2048), dim3(256), 0, stream>>>(inp, b1, g1, be1, Watt1, batt1, g2, be2, Watt2, batt2, ws);
  k_reduce<<<dim3(1), dim3(256), 0, stream>>>(ws);
  k_gather<<<dim3(512), dim3(256), 0, stream>>>(ws);
  k_exact<<<dim3(512), dim3(256), 0, stream>>>(inp, W1, b1, g1, be1, Watt1, batt1, g2, be2, Watt2, batt2, ws);
  k_select<<<dim3(1), dim3(256), 0, stream>>>(ws);
  k_zs<<<dim3(64), dim3(256), 0, stream>>>(inp, W1, b1, g1, be1, Wq, Wk, Wv, ws);
  k_attn<<<dim3(1), dim3(256), 0, stream>>>(ws, (float*)d_out);
  k_wz<<<dim3(128), dim3(256), 0, stream>>>(Wz, bz, Wf, bf_, ws, (float*)d_out);
}